// Round 18
// baseline (157.891 us; speedup 1.0000x reference)
//
#include <hip/hip_runtime.h>

static constexpr int NN  = 100000;   // nodes
static constexpr int NE  = 1200000;  // edges
static constexpr int KIN = 256;      // input dim
static constexpr int HID = 64;       // hidden == output dim

static constexpr int BSH   = 7;                        // log2 nodes-per-bucket
static constexpr int NPB   = 1 << BSH;                 // 128 nodes per bucket
static constexpr int NB    = (NN + NPB - 1) / NPB;     // 782 buckets
static constexpr int CAP   = 4096;                     // fixed edge capacity per bucket
static constexpr int CHUNK = 8192;                     // edges per binning block
static constexpr int NBK   = (NE + CHUNK - 1) / CHUNK; // 147 binning blocks

typedef __attribute__((ext_vector_type(8))) __bf16 bf16v8;
typedef __attribute__((ext_vector_type(4))) float f32x4;

// ---------- bf16 helpers (exact widen; RNE narrow)
__device__ __forceinline__ float bf2f(unsigned short u) {
  return __uint_as_float(((unsigned int)u) << 16);
}
__device__ __forceinline__ unsigned short f2bf(float f) {
  unsigned int b = __float_as_uint(f);
  return (unsigned short)((b + 0x7FFFu + ((b >> 16) & 1u)) >> 16);
}

// ---------- W tables fp32 -> bf16 hi/lo + zero the bucket cursors (one launch)
__global__ void k_wconv2z(const float* __restrict__ W1, __bf16* __restrict__ Whi1, __bf16* __restrict__ Wlo1,
                          const float* __restrict__ W2, __bf16* __restrict__ Whi2, __bf16* __restrict__ Wlo2,
                          int* __restrict__ gcur) {
  int i = blockIdx.x * 256 + threadIdx.x;
  constexpr int n1 = HID * KIN;
  if (i < n1) {
    float v = W1[i];
    __bf16 h = (__bf16)v;
    Whi1[i] = h;
    Wlo1[i] = (__bf16)(v - (float)h);
  } else if (i < n1 + HID * HID) {
    int j = i - n1;
    float v = W2[j];
    __bf16 h = (__bf16)v;
    Whi2[j] = h;
    Wlo2[j] = (__bf16)(v - (float)h);
  }
  if (i < NB) gcur[i] = 0;
}

// ---------- single-pass binning into fixed-capacity bucket regions.
__global__ void __launch_bounds__(256) k_bin1p(const int* __restrict__ ed, int* __restrict__ gcur,
                                               unsigned* __restrict__ binned) {
  __shared__ int lcnt[NB];
  __shared__ int lbase[NB];
  int t = threadIdx.x, blk = blockIdx.x;
  for (int i = t; i < NB; i += 256) lcnt[i] = 0;
  __syncthreads();
  int base = blk * CHUNK;
  #pragma unroll
  for (int it = 0; it < CHUNK / 256; ++it) {          // pass 1: count
    int e = base + it * 256 + t;
    if (e < NE) atomicAdd(&lcnt[ed[NE + e] >> BSH], 1);
  }
  __syncthreads();
  for (int i = t; i < NB; i += 256) {                  // reserve ranges
    int c = lcnt[i];
    lbase[i] = (c > 0) ? atomicAdd(&gcur[i], c) : 0;
    lcnt[i] = 0;                                       // reuse as rank counter
  }
  __syncthreads();
  #pragma unroll
  for (int it = 0; it < CHUNK / 256; ++it) {          // pass 2: scatter (ed chunk L2-hot)
    int e = base + it * 256 + t;
    if (e < NE) {
      int src = ed[e];
      int dst = ed[NE + e];
      int b = dst >> BSH;
      int r = atomicAdd(&lcnt[b], 1);
      binned[(size_t)b * CAP + lbase[b] + r] = (unsigned)src | ((unsigned)(dst & (NPB - 1)) << 17);
    }
  }
}

// ---------- fused per-bucket: degree + dinv + rp + CSR scatter (window L2-hot)
__global__ void __launch_bounds__(256) k_degcsr(const unsigned* __restrict__ binned,
                                                const int* __restrict__ gcur,
                                                int* __restrict__ deg, float* __restrict__ dinv,
                                                int* __restrict__ rp, int* __restrict__ csr) {
  __shared__ int d[NPB];
  __shared__ int sc[NPB];
  __shared__ int cur[NPB];
  int t = threadIdx.x, b = blockIdx.x;
  if (t < NPB) { d[t] = 0; cur[t] = 0; }
  __syncthreads();
  const int n = gcur[b];
  const unsigned* win = binned + (size_t)b * CAP;
  for (int i = t; i < n; i += 256) atomicAdd(&d[win[i] >> 17], 1);
  __syncthreads();
  if (t < NPB) sc[t] = d[t];
  __syncthreads();
  #pragma unroll
  for (int off = 1; off < NPB; off <<= 1) {
    int x = (t < NPB && t >= off) ? sc[t - off] : 0;
    __syncthreads();
    if (t < NPB) sc[t] += x;
    __syncthreads();
  }
  if (t < NPB) {
    int node = b * NPB + t;
    if (node < NN) {
      deg[node] = d[t];
      dinv[node] = rsqrtf((float)(d[t] + 1));
      rp[node] = b * CAP + sc[t] - d[t];
    }
  }
  __syncthreads();
  for (int i = t; i < n; i += 256) {
    unsigned u = win[i];
    int src = (int)(u & 0x1FFFFu);
    int dl  = (int)(u >> 17);
    int r = atomicAdd(&cur[dl], 1);
    csr[(size_t)b * CAP + (sc[dl] - d[dl]) + r] = src;
  }
}

// ---------- MFMA GEMM with register prefetch of next k-tile.
// Y = X @ W^T via bf16 hi/lo 3-term split (~fp32 accurate).
// MODE 0: Y(bf16) = dinv[r]*acc; MODE 1: Y(fp32) = relu(acc + bias).
template<int K, int MODE>
__global__ void __launch_bounds__(256, 4)
k_gemm(const float* __restrict__ X, const __bf16* __restrict__ Whi, const __bf16* __restrict__ Wlo,
       const float* __restrict__ dinv, const float* __restrict__ bias, void* __restrict__ Yv) {
  constexpr int KT = 32;
  constexpr int NT = K / KT;
  constexpr int LS = 40;
  constexpr int CS = 68;
  __shared__ __align__(16) char smem[4 * 64 * LS * 2];
  __bf16* xh = (__bf16*)smem;
  __bf16* xl = xh + 64 * LS;
  __bf16* wh = xl + 64 * LS;
  __bf16* wl = wh + 64 * LS;
  float*  cl = (float*)smem;

  const int t = threadIdx.x;
  const int l = t & 63;
  const int wc = (t >> 6) * 16;
  const int rowbase = blockIdx.x * 64;

  f32x4 acc[4];
  #pragma unroll
  for (int rt = 0; rt < 4; ++rt) acc[rt] = (f32x4){0.f, 0.f, 0.f, 0.f};

  const int sr = t >> 2;
  const int kc = (t & 3) * 8;
  const int gr = rowbase + sr;
  const float* xrow = X + (size_t)gr * K + kc;

  float4 pa, pb;
  bf16v8 pwh, pwl;

  auto loadTile = [&](int kt) {
    pa = make_float4(0.f, 0.f, 0.f, 0.f);
    pb = pa;
    if (gr < NN) {
      pa = *reinterpret_cast<const float4*>(xrow + kt * KT);
      pb = *reinterpret_cast<const float4*>(xrow + kt * KT + 4);
    }
    size_t wo = (size_t)sr * K + kt * KT + kc;
    pwh = *reinterpret_cast<const bf16v8*>(Whi + wo);
    pwl = *reinterpret_cast<const bf16v8*>(Wlo + wo);
  };
  auto storeTile = [&]() {
    float e[8] = {pa.x, pa.y, pa.z, pa.w, pb.x, pb.y, pb.z, pb.w};
    bf16v8 hv, lv;
    #pragma unroll
    for (int j = 0; j < 8; ++j) {
      __bf16 h = (__bf16)e[j];
      hv[j] = h;
      lv[j] = (__bf16)(e[j] - (float)h);
    }
    *reinterpret_cast<bf16v8*>(&xh[sr * LS + kc]) = hv;
    *reinterpret_cast<bf16v8*>(&xl[sr * LS + kc]) = lv;
    *reinterpret_cast<bf16v8*>(&wh[sr * LS + kc]) = pwh;
    *reinterpret_cast<bf16v8*>(&wl[sr * LS + kc]) = pwl;
  };

  loadTile(0);
  storeTile();
  __syncthreads();

  for (int kt = 0; kt < NT; ++kt) {
    if (kt + 1 < NT) loadTile(kt + 1);   // global loads in flight during compute

    const int bo = (wc + (l & 15)) * LS + (l >> 4) * 8;
    bf16v8 bh = *reinterpret_cast<const bf16v8*>(&wh[bo]);
    bf16v8 bl = *reinterpret_cast<const bf16v8*>(&wl[bo]);
    #pragma unroll
    for (int rt = 0; rt < 4; ++rt) {
      const int ao = (rt * 16 + (l & 15)) * LS + (l >> 4) * 8;
      bf16v8 ah = *reinterpret_cast<const bf16v8*>(&xh[ao]);
      bf16v8 al = *reinterpret_cast<const bf16v8*>(&xl[ao]);
      acc[rt] = __builtin_amdgcn_mfma_f32_16x16x32_bf16(ah, bh, acc[rt], 0, 0, 0);
      acc[rt] = __builtin_amdgcn_mfma_f32_16x16x32_bf16(al, bh, acc[rt], 0, 0, 0);
      acc[rt] = __builtin_amdgcn_mfma_f32_16x16x32_bf16(ah, bl, acc[rt], 0, 0, 0);
    }

    if (kt + 1 < NT) {
      __syncthreads();                   // tile kt fully consumed
      storeTile();
      __syncthreads();                   // tile kt+1 visible
    }
  }

  __syncthreads();
  #pragma unroll
  for (int rt = 0; rt < 4; ++rt)
    #pragma unroll
    for (int j = 0; j < 4; ++j)
      cl[(rt * 16 + (l >> 4) * 4 + j) * CS + wc + (l & 15)] = acc[rt][j];
  __syncthreads();

  const int r = t >> 2, cc = (t & 3) * 16;
  const int grow = rowbase + r;
  if (grow < NN) {
    if (MODE == 0) {
      float dv = dinv[grow];
      bf16v8 o0, o1;
      #pragma unroll
      for (int j = 0; j < 8; ++j) o0[j] = (__bf16)(cl[r * CS + cc + j] * dv);
      #pragma unroll
      for (int j = 0; j < 8; ++j) o1[j] = (__bf16)(cl[r * CS + cc + 8 + j] * dv);
      __bf16* yp = (__bf16*)Yv + (size_t)grow * HID + cc;
      *reinterpret_cast<bf16v8*>(yp) = o0;
      *reinterpret_cast<bf16v8*>(yp + 8) = o1;
    } else {
      float* yp = (float*)Yv + (size_t)grow * HID + cc;
      #pragma unroll
      for (int c4 = 0; c4 < 4; ++c4) {
        float4 o;
        o.x = fmaxf(cl[r * CS + cc + c4 * 4 + 0] + bias[cc + c4 * 4 + 0], 0.f);
        o.y = fmaxf(cl[r * CS + cc + c4 * 4 + 1] + bias[cc + c4 * 4 + 1], 0.f);
        o.z = fmaxf(cl[r * CS + cc + c4 * 4 + 2] + bias[cc + c4 * 4 + 2], 0.f);
        o.w = fmaxf(cl[r * CS + cc + c4 * 4 + 3] + bias[cc + c4 * 4 + 3], 0.f);
        *reinterpret_cast<float4*>(yp + c4 * 4) = o;
      }
    }
  }
}

// ---------- standalone agg (layer 1), PAIR-PIPELINED: each wave interleaves TWO nodes'
// gather batches (~32 loads in flight vs 16; per-node depth is deg-capped ~12).
// All pair branches are wave-uniform -> no exec-mask divergence (round-15 lesson).
// O(bf16) = dinv*relu(dinv*sum + bias)
__global__ void __launch_bounds__(256, 6)
k_agg(const unsigned short* __restrict__ T, const int* __restrict__ csr,
      const int* __restrict__ rp, const int* __restrict__ deg,
      const float* __restrict__ dinv, const float* __restrict__ bias,
      unsigned short* __restrict__ Ov) {
  const int lane = threadIdx.x & 63;
  const int n0 = blockIdx.x * 8 + (threadIdx.x >> 6) * 2;
  const int n1 = n0 + 1;
  float acc0 = bf2f(T[(size_t)n0 * HID + lane]);
  float acc1 = bf2f(T[(size_t)n1 * HID + lane]);
  const int s0 = rp[n0], l0 = deg[n0];
  const int s1 = rp[n1], l1 = deg[n1];
  const int lmax = max(l0, l1);
  for (int base = 0; base < lmax; base += 64) {
    const int m0 = min(64, l0 - base);   // may be <=0 (inactive)
    const int m1 = min(64, l1 - base);
    int idx0 = (lane < m0) ? csr[s0 + base + lane] : 0;
    int idx1 = (lane < m1) ? csr[s1 + base + lane] : 0;
    const int cmax = max(m0, m1);
    for (int c0 = 0; c0 < cmax; c0 += 16) {
      float v0[16], v1[16];
      const bool a0 = c0 < m0, a1 = c0 < m1;   // wave-uniform
      if (a0) {
        #pragma unroll
        for (int i = 0; i < 16; ++i) {
          int s = __shfl(idx0, (c0 + i) & 63);
          v0[i] = bf2f(T[(size_t)s * HID + lane]);
        }
      }
      if (a1) {
        #pragma unroll
        for (int i = 0; i < 16; ++i) {
          int s = __shfl(idx1, (c0 + i) & 63);
          v1[i] = bf2f(T[(size_t)s * HID + lane]);
        }
      }
      if (a0) {
        float p = 0.f;
        #pragma unroll
        for (int i = 0; i < 16; ++i) p += (c0 + i < m0) ? v0[i] : 0.f;
        acc0 += p;
      }
      if (a1) {
        float p = 0.f;
        #pragma unroll
        for (int i = 0; i < 16; ++i) p += (c0 + i < m1) ? v1[i] : 0.f;
        acc1 += p;
      }
    }
  }
  float dv0 = dinv[n0];
  Ov[(size_t)n0 * HID + lane] = f2bf(dv0 * fmaxf(fmaf(dv0, acc0, bias[lane]), 0.f));
  float dv1 = dinv[n1];
  Ov[(size_t)n1 * HID + lane] = f2bf(dv1 * fmaxf(fmaf(dv1, acc1, bias[lane]), 0.f));
}

// ---------- FUSED agg(layer2) + GEMM2: block = 64 nodes.
// Phase A: wave w computes g rows [w*16, w*16+16) as 8 PAIR-PIPELINED node pairs,
//          writes bf16 hi/lo to LDS.  g = dinv .* (Agg Hp)
// Phase B: out = relu(g @ W2^T + b2); W2 hi/lo frags read from global (8 KB, L1-hot).
__global__ void __launch_bounds__(256, 6)
k_aggemm(const unsigned short* __restrict__ T, const int* __restrict__ csr,
         const int* __restrict__ rp, const int* __restrict__ deg,
         const float* __restrict__ dinv,
         const __bf16* __restrict__ Whi2, const __bf16* __restrict__ Wlo2,
         const float* __restrict__ bias, float* __restrict__ out) {
  constexpr int LS = 72;                 // bf16 row stride for g tiles
  constexpr int CS = 68;                 // epilogue f32 row stride
  __shared__ __align__(16) char smem[2 * 64 * LS * 2];   // 18432 B
  __bf16* gh = (__bf16*)smem;
  __bf16* gl = gh + 64 * LS;
  float*  cl = (float*)smem;             // epilogue overlay (17408 B)

  const int t = threadIdx.x;
  const int l = t & 63;
  const int w = t >> 6;
  const int rowbase = blockIdx.x * 64;

  // ---- phase A: 8 node pairs per wave
  for (int i = 0; i < 16; i += 2) {
    const int n0 = rowbase + w * 16 + i;
    const int n1 = n0 + 1;
    const bool va0 = n0 < NN, va1 = n1 < NN;
    float acc0 = va0 ? bf2f(T[(size_t)n0 * HID + l]) : 0.f;
    float acc1 = va1 ? bf2f(T[(size_t)n1 * HID + l]) : 0.f;
    const int s0 = va0 ? rp[n0] : 0, l0 = va0 ? deg[n0] : 0;
    const int s1 = va1 ? rp[n1] : 0, l1 = va1 ? deg[n1] : 0;
    const int lmax = max(l0, l1);
    for (int base = 0; base < lmax; base += 64) {
      const int m0 = min(64, l0 - base);
      const int m1 = min(64, l1 - base);
      int idx0 = (l < m0) ? csr[s0 + base + l] : 0;
      int idx1 = (l < m1) ? csr[s1 + base + l] : 0;
      const int cmax = max(m0, m1);
      for (int c0 = 0; c0 < cmax; c0 += 16) {
        float v0[16], v1[16];
        const bool a0 = c0 < m0, a1 = c0 < m1;
        if (a0) {
          #pragma unroll
          for (int j = 0; j < 16; ++j) {
            int s = __shfl(idx0, (c0 + j) & 63);
            v0[j] = bf2f(T[(size_t)s * HID + l]);
          }
        }
        if (a1) {
          #pragma unroll
          for (int j = 0; j < 16; ++j) {
            int s = __shfl(idx1, (c0 + j) & 63);
            v1[j] = bf2f(T[(size_t)s * HID + l]);
          }
        }
        if (a0) {
          float p = 0.f;
          #pragma unroll
          for (int j = 0; j < 16; ++j) p += (c0 + j < m0) ? v0[j] : 0.f;
          acc0 += p;
        }
        if (a1) {
          float p = 0.f;
          #pragma unroll
          for (int j = 0; j < 16; ++j) p += (c0 + j < m1) ? v1[j] : 0.f;
          acc1 += p;
        }
      }
    }
    float g0 = va0 ? dinv[n0] * acc0 : 0.f;
    float g1 = va1 ? dinv[n1] * acc1 : 0.f;
    __bf16 h0 = (__bf16)g0, h1 = (__bf16)g1;
    const int r0 = w * 16 + i;
    gh[r0 * LS + l] = h0;
    gl[r0 * LS + l] = (__bf16)(g0 - (float)h0);
    gh[(r0 + 1) * LS + l] = h1;
    gl[(r0 + 1) * LS + l] = (__bf16)(g1 - (float)h1);
  }
  __syncthreads();

  // ---- phase B: MFMA, wave = 16-col slab
  const int wc = w * 16;
  f32x4 acc[4];
  #pragma unroll
  for (int rt = 0; rt < 4; ++rt) acc[rt] = (f32x4){0.f, 0.f, 0.f, 0.f};
  #pragma unroll
  for (int kc = 0; kc < 2; ++kc) {
    const size_t wo = (size_t)(wc + (l & 15)) * HID + kc * 32 + (l >> 4) * 8;
    bf16v8 bh = *reinterpret_cast<const bf16v8*>(Whi2 + wo);
    bf16v8 bl = *reinterpret_cast<const bf16v8*>(Wlo2 + wo);
    #pragma unroll
    for (int rt = 0; rt < 4; ++rt) {
      const int ao = (rt * 16 + (l & 15)) * LS + kc * 32 + (l >> 4) * 8;
      bf16v8 ah = *reinterpret_cast<const bf16v8*>(&gh[ao]);
      bf16v8 al = *reinterpret_cast<const bf16v8*>(&gl[ao]);
      acc[rt] = __builtin_amdgcn_mfma_f32_16x16x32_bf16(ah, bh, acc[rt], 0, 0, 0);
      acc[rt] = __builtin_amdgcn_mfma_f32_16x16x32_bf16(al, bh, acc[rt], 0, 0, 0);
      acc[rt] = __builtin_amdgcn_mfma_f32_16x16x32_bf16(ah, bl, acc[rt], 0, 0, 0);
    }
  }
  __syncthreads();                       // gh/gl dead; overlay cl
  #pragma unroll
  for (int rt = 0; rt < 4; ++rt)
    #pragma unroll
    for (int j = 0; j < 4; ++j)
      cl[(rt * 16 + (l >> 4) * 4 + j) * CS + wc + (l & 15)] = acc[rt][j];
  __syncthreads();

  const int r = t >> 2, cc = (t & 3) * 16;
  const int grow = rowbase + r;
  if (grow < NN) {
    float* yp = out + (size_t)grow * HID + cc;
    #pragma unroll
    for (int c4 = 0; c4 < 4; ++c4) {
      float4 o;
      o.x = fmaxf(cl[r * CS + cc + c4 * 4 + 0] + bias[cc + c4 * 4 + 0], 0.f);
      o.y = fmaxf(cl[r * CS + cc + c4 * 4 + 1] + bias[cc + c4 * 4 + 1], 0.f);
      o.z = fmaxf(cl[r * CS + cc + c4 * 4 + 2] + bias[cc + c4 * 4 + 2], 0.f);
      o.w = fmaxf(cl[r * CS + cc + c4 * 4 + 3] + bias[cc + c4 * 4 + 3], 0.f);
      *reinterpret_cast<float4*>(yp + c4 * 4) = o;
    }
  }
}

extern "C" void kernel_launch(void* const* d_in, const int* in_sizes, int n_in,
                              void* d_out, int out_size, void* d_ws, size_t ws_size,
                              hipStream_t stream) {
  const float* x  = (const float*)d_in[0];
  const int*   ed = (const int*)d_in[1];   // int32 per harness contract
  const float* W1 = (const float*)d_in[2];
  const float* b1 = (const float*)d_in[3];
  const float* W2 = (const float*)d_in[4];
  const float* b2 = (const float*)d_in[5];
  float* out = (float*)d_out;

  char* ws = (char*)d_ws;
  size_t off = 0;
  auto alloc = [&](size_t bytes) {
    char* p = ws + off;
    off = (off + bytes + 255) & ~(size_t)255;
    return p;
  };
  int*      deg    = (int*)alloc((size_t)NN * 4);
  float*    dinv   = (float*)alloc((size_t)NN * 4);
  int*      rp     = (int*)alloc((size_t)NN * 4);
  int*      gcur   = (int*)alloc((size_t)NB * 4);
  unsigned* binned = (unsigned*)alloc((size_t)NB * CAP * 4);     // 12.8 MB
  int*      csr    = (int*)alloc((size_t)NB * CAP * 4);          // 12.8 MB
  unsigned short* T1 = (unsigned short*)alloc((size_t)NN * HID * 2);  // 12.8 MB bf16 t1'
  unsigned short* Hp = (unsigned short*)alloc((size_t)NN * HID * 2);  // 12.8 MB bf16 h'
  __bf16*   Whi1   = (__bf16*)alloc((size_t)HID * KIN * 2);
  __bf16*   Wlo1   = (__bf16*)alloc((size_t)HID * KIN * 2);
  __bf16*   Whi2   = (__bf16*)alloc((size_t)HID * HID * 2);
  __bf16*   Wlo2   = (__bf16*)alloc((size_t)HID * HID * 2);

  // ---- preprocessing: 3 launches
  k_wconv2z<<<(HID * KIN + HID * HID + 255) / 256, 256, 0, stream>>>(W1, Whi1, Wlo1, W2, Whi2, Wlo2, gcur);
  k_bin1p<<<NBK, 256, 0, stream>>>(ed, gcur, binned);
  k_degcsr<<<NB, 256, 0, stream>>>(binned, gcur, deg, dinv, rp, csr);

  const int GB = (NN + 63) / 64;  // 1563 blocks

  // layer 1: T1(bf16) = dinv .* (x @ W1^T) ; Hp(bf16) = dinv .* relu(dinv.*(Agg T1) + b1)
  k_gemm<KIN, 0><<<GB, 256, 0, stream>>>(x, Whi1, Wlo1, dinv, b1, (void*)T1);
  k_agg<<<NN / 8, 256, 0, stream>>>(T1, csr, rp, deg, dinv, b1, Hp);

  // layer 2 fused: out = relu((dinv .* Agg Hp) @ W2^T + b2)
  k_aggemm<<<GB, 256, 0, stream>>>(Hp, csr, rp, deg, dinv, Whi2, Wlo2, b2, out);
}

// Round 19
// 145.522 us; speedup vs baseline: 1.0850x; 1.0850x over previous
//
#include <hip/hip_runtime.h>

static constexpr int NN  = 100000;   // nodes
static constexpr int NE  = 1200000;  // edges
static constexpr int KIN = 256;      // input dim
static constexpr int HID = 64;       // hidden == output dim

static constexpr int BSH   = 7;                        // log2 nodes-per-bucket
static constexpr int NPB   = 1 << BSH;                 // 128 nodes per bucket
static constexpr int NB    = (NN + NPB - 1) / NPB;     // 782 buckets
static constexpr int CAP   = 4096;                     // fixed edge capacity per bucket
static constexpr int CHUNK = 8192;                     // edges per binning block
static constexpr int NBK   = (NE + CHUNK - 1) / CHUNK; // 147 binning blocks

typedef __attribute__((ext_vector_type(8))) __bf16 bf16v8;
typedef __attribute__((ext_vector_type(4))) float f32x4;

// ---------- bf16 helpers (exact widen; RNE narrow)
__device__ __forceinline__ float bf2f(unsigned short u) {
  return __uint_as_float(((unsigned int)u) << 16);
}
__device__ __forceinline__ unsigned short f2bf(float f) {
  unsigned int b = __float_as_uint(f);
  return (unsigned short)((b + 0x7FFFu + ((b >> 16) & 1u)) >> 16);
}

// ---------- W tables fp32 -> bf16 hi/lo + zero the bucket cursors (one launch)
__global__ void k_wconv2z(const float* __restrict__ W1, __bf16* __restrict__ Whi1, __bf16* __restrict__ Wlo1,
                          const float* __restrict__ W2, __bf16* __restrict__ Whi2, __bf16* __restrict__ Wlo2,
                          int* __restrict__ gcur) {
  int i = blockIdx.x * 256 + threadIdx.x;
  constexpr int n1 = HID * KIN;
  if (i < n1) {
    float v = W1[i];
    __bf16 h = (__bf16)v;
    Whi1[i] = h;
    Wlo1[i] = (__bf16)(v - (float)h);
  } else if (i < n1 + HID * HID) {
    int j = i - n1;
    float v = W2[j];
    __bf16 h = (__bf16)v;
    Whi2[j] = h;
    Wlo2[j] = (__bf16)(v - (float)h);
  }
  if (i < NB) gcur[i] = 0;
}

// ---------- single-pass binning into fixed-capacity bucket regions.
__global__ void __launch_bounds__(256) k_bin1p(const int* __restrict__ ed, int* __restrict__ gcur,
                                               unsigned* __restrict__ binned) {
  __shared__ int lcnt[NB];
  __shared__ int lbase[NB];
  int t = threadIdx.x, blk = blockIdx.x;
  for (int i = t; i < NB; i += 256) lcnt[i] = 0;
  __syncthreads();
  int base = blk * CHUNK;
  #pragma unroll
  for (int it = 0; it < CHUNK / 256; ++it) {          // pass 1: count
    int e = base + it * 256 + t;
    if (e < NE) atomicAdd(&lcnt[ed[NE + e] >> BSH], 1);
  }
  __syncthreads();
  for (int i = t; i < NB; i += 256) {                  // reserve ranges
    int c = lcnt[i];
    lbase[i] = (c > 0) ? atomicAdd(&gcur[i], c) : 0;
    lcnt[i] = 0;                                       // reuse as rank counter
  }
  __syncthreads();
  #pragma unroll
  for (int it = 0; it < CHUNK / 256; ++it) {          // pass 2: scatter (ed chunk L2-hot)
    int e = base + it * 256 + t;
    if (e < NE) {
      int src = ed[e];
      int dst = ed[NE + e];
      int b = dst >> BSH;
      int r = atomicAdd(&lcnt[b], 1);
      binned[(size_t)b * CAP + lbase[b] + r] = (unsigned)src | ((unsigned)(dst & (NPB - 1)) << 17);
    }
  }
}

// ---------- fused per-bucket: degree + dinv + rp + CSR scatter (window L2-hot)
__global__ void __launch_bounds__(256) k_degcsr(const unsigned* __restrict__ binned,
                                                const int* __restrict__ gcur,
                                                int* __restrict__ deg, float* __restrict__ dinv,
                                                int* __restrict__ rp, int* __restrict__ csr) {
  __shared__ int d[NPB];
  __shared__ int sc[NPB];
  __shared__ int cur[NPB];
  int t = threadIdx.x, b = blockIdx.x;
  if (t < NPB) { d[t] = 0; cur[t] = 0; }
  __syncthreads();
  const int n = gcur[b];
  const unsigned* win = binned + (size_t)b * CAP;
  for (int i = t; i < n; i += 256) atomicAdd(&d[win[i] >> 17], 1);
  __syncthreads();
  if (t < NPB) sc[t] = d[t];
  __syncthreads();
  #pragma unroll
  for (int off = 1; off < NPB; off <<= 1) {
    int x = (t < NPB && t >= off) ? sc[t - off] : 0;
    __syncthreads();
    if (t < NPB) sc[t] += x;
    __syncthreads();
  }
  if (t < NPB) {
    int node = b * NPB + t;
    if (node < NN) {
      deg[node] = d[t];
      dinv[node] = rsqrtf((float)(d[t] + 1));
      rp[node] = b * CAP + sc[t] - d[t];
    }
  }
  __syncthreads();
  for (int i = t; i < n; i += 256) {
    unsigned u = win[i];
    int src = (int)(u & 0x1FFFFu);
    int dl  = (int)(u >> 17);
    int r = atomicAdd(&cur[dl], 1);
    csr[(size_t)b * CAP + (sc[dl] - d[dl]) + r] = src;
  }
}

// ---------- MFMA GEMM with register prefetch of next k-tile.
// Y = X @ W^T via bf16 hi/lo 3-term split (~fp32 accurate).
// MODE 0: Y(bf16) = dinv[r]*acc; MODE 1: Y(fp32) = relu(acc + bias).
template<int K, int MODE>
__global__ void __launch_bounds__(256, 4)
k_gemm(const float* __restrict__ X, const __bf16* __restrict__ Whi, const __bf16* __restrict__ Wlo,
       const float* __restrict__ dinv, const float* __restrict__ bias, void* __restrict__ Yv) {
  constexpr int KT = 32;
  constexpr int NT = K / KT;
  constexpr int LS = 40;
  constexpr int CS = 68;
  __shared__ __align__(16) char smem[4 * 64 * LS * 2];
  __bf16* xh = (__bf16*)smem;
  __bf16* xl = xh + 64 * LS;
  __bf16* wh = xl + 64 * LS;
  __bf16* wl = wh + 64 * LS;
  float*  cl = (float*)smem;

  const int t = threadIdx.x;
  const int l = t & 63;
  const int wc = (t >> 6) * 16;
  const int rowbase = blockIdx.x * 64;

  f32x4 acc[4];
  #pragma unroll
  for (int rt = 0; rt < 4; ++rt) acc[rt] = (f32x4){0.f, 0.f, 0.f, 0.f};

  const int sr = t >> 2;
  const int kc = (t & 3) * 8;
  const int gr = rowbase + sr;
  const float* xrow = X + (size_t)gr * K + kc;

  float4 pa, pb;
  bf16v8 pwh, pwl;

  auto loadTile = [&](int kt) {
    pa = make_float4(0.f, 0.f, 0.f, 0.f);
    pb = pa;
    if (gr < NN) {
      pa = *reinterpret_cast<const float4*>(xrow + kt * KT);
      pb = *reinterpret_cast<const float4*>(xrow + kt * KT + 4);
    }
    size_t wo = (size_t)sr * K + kt * KT + kc;
    pwh = *reinterpret_cast<const bf16v8*>(Whi + wo);
    pwl = *reinterpret_cast<const bf16v8*>(Wlo + wo);
  };
  auto storeTile = [&]() {
    float e[8] = {pa.x, pa.y, pa.z, pa.w, pb.x, pb.y, pb.z, pb.w};
    bf16v8 hv, lv;
    #pragma unroll
    for (int j = 0; j < 8; ++j) {
      __bf16 h = (__bf16)e[j];
      hv[j] = h;
      lv[j] = (__bf16)(e[j] - (float)h);
    }
    *reinterpret_cast<bf16v8*>(&xh[sr * LS + kc]) = hv;
    *reinterpret_cast<bf16v8*>(&xl[sr * LS + kc]) = lv;
    *reinterpret_cast<bf16v8*>(&wh[sr * LS + kc]) = pwh;
    *reinterpret_cast<bf16v8*>(&wl[sr * LS + kc]) = pwl;
  };

  loadTile(0);
  storeTile();
  __syncthreads();

  for (int kt = 0; kt < NT; ++kt) {
    if (kt + 1 < NT) loadTile(kt + 1);   // global loads in flight during compute

    const int bo = (wc + (l & 15)) * LS + (l >> 4) * 8;
    bf16v8 bh = *reinterpret_cast<const bf16v8*>(&wh[bo]);
    bf16v8 bl = *reinterpret_cast<const bf16v8*>(&wl[bo]);
    #pragma unroll
    for (int rt = 0; rt < 4; ++rt) {
      const int ao = (rt * 16 + (l & 15)) * LS + (l >> 4) * 8;
      bf16v8 ah = *reinterpret_cast<const bf16v8*>(&xh[ao]);
      bf16v8 al = *reinterpret_cast<const bf16v8*>(&xl[ao]);
      acc[rt] = __builtin_amdgcn_mfma_f32_16x16x32_bf16(ah, bh, acc[rt], 0, 0, 0);
      acc[rt] = __builtin_amdgcn_mfma_f32_16x16x32_bf16(al, bh, acc[rt], 0, 0, 0);
      acc[rt] = __builtin_amdgcn_mfma_f32_16x16x32_bf16(ah, bl, acc[rt], 0, 0, 0);
    }

    if (kt + 1 < NT) {
      __syncthreads();                   // tile kt fully consumed
      storeTile();
      __syncthreads();                   // tile kt+1 visible
    }
  }

  __syncthreads();
  #pragma unroll
  for (int rt = 0; rt < 4; ++rt)
    #pragma unroll
    for (int j = 0; j < 4; ++j)
      cl[(rt * 16 + (l >> 4) * 4 + j) * CS + wc + (l & 15)] = acc[rt][j];
  __syncthreads();

  const int r = t >> 2, cc = (t & 3) * 16;
  const int grow = rowbase + r;
  if (grow < NN) {
    if (MODE == 0) {
      float dv = dinv[grow];
      bf16v8 o0, o1;
      #pragma unroll
      for (int j = 0; j < 8; ++j) o0[j] = (__bf16)(cl[r * CS + cc + j] * dv);
      #pragma unroll
      for (int j = 0; j < 8; ++j) o1[j] = (__bf16)(cl[r * CS + cc + 8 + j] * dv);
      __bf16* yp = (__bf16*)Yv + (size_t)grow * HID + cc;
      *reinterpret_cast<bf16v8*>(yp) = o0;
      *reinterpret_cast<bf16v8*>(yp + 8) = o1;
    } else {
      float* yp = (float*)Yv + (size_t)grow * HID + cc;
      #pragma unroll
      for (int c4 = 0; c4 < 4; ++c4) {
        float4 o;
        o.x = fmaxf(cl[r * CS + cc + c4 * 4 + 0] + bias[cc + c4 * 4 + 0], 0.f);
        o.y = fmaxf(cl[r * CS + cc + c4 * 4 + 1] + bias[cc + c4 * 4 + 1], 0.f);
        o.z = fmaxf(cl[r * CS + cc + c4 * 4 + 2] + bias[cc + c4 * 4 + 2], 0.f);
        o.w = fmaxf(cl[r * CS + cc + c4 * 4 + 3] + bias[cc + c4 * 4 + 3], 0.f);
        *reinterpret_cast<float4*>(yp + c4 * 4) = o;
      }
    }
  }
}

// ---------- standalone agg (layer 1), U32-PAIRED gathers: lane = (edge-slot l>>5,
// feature-pair l&31). One dword gather = 2 edges x full 64-feature row (256 B) and the
// u32 unpack gives both bf16 features in 2 VALU ops. Loop bounds node-uniform -> no
// divergence. One shfl_xor(32) merges slots. O(bf16) = dinv*relu(dinv*sum + bias).
__global__ void __launch_bounds__(256, 8)
k_agg(const unsigned* __restrict__ T32, const int* __restrict__ csr,
      const int* __restrict__ rp, const int* __restrict__ deg,
      const float* __restrict__ dinv, const float* __restrict__ bias,
      unsigned* __restrict__ Ov32) {
  const int t = threadIdx.x;
  const int node = blockIdx.x * 4 + (t >> 6);
  const int lane = t & 63;
  const int s = lane >> 5;          // edge slot (0/1)
  const int fp = lane & 31;         // feature pair index
  float acc0 = 0.f, acc1 = 0.f;
  const int start = rp[node];
  const int len = deg[node];
  for (int base = 0; base < len; base += 64) {
    int m = min(64, len - base);
    int idx = (lane < m) ? csr[start + base + lane] : 0;
    for (int c0 = 0; c0 < m; c0 += 16) {     // 16 edges per outer iter = 8 gather instrs
      float p0 = 0.f, p1 = 0.f;
      #pragma unroll
      for (int i = 0; i < 8; ++i) {
        int e = c0 + 2 * i + s;
        int src = __shfl(idx, e & 63);
        unsigned u = T32[(size_t)src * 32 + fp];     // 2 bf16 features
        bool ok = e < m;
        p0 += ok ? __uint_as_float(u << 16) : 0.f;
        p1 += ok ? __uint_as_float(u & 0xFFFF0000u) : 0.f;
      }
      acc0 += p0;
      acc1 += p1;
    }
  }
  acc0 += __shfl_xor(acc0, 32);       // merge edge slots
  acc1 += __shfl_xor(acc1, 32);
  unsigned su = T32[(size_t)node * 32 + fp];   // self-loop (pre-scaled)
  acc0 += __uint_as_float(su << 16);
  acc1 += __uint_as_float(su & 0xFFFF0000u);
  float dv = dinv[node];
  float h0 = dv * fmaxf(fmaf(dv, acc0, bias[fp * 2]), 0.f);
  float h1 = dv * fmaxf(fmaf(dv, acc1, bias[fp * 2 + 1]), 0.f);
  if (s == 0) {
    unsigned pack = (unsigned)f2bf(h0) | ((unsigned)f2bf(h1) << 16);
    Ov32[(size_t)node * 32 + fp] = pack;
  }
}

// ---------- FUSED agg(layer2) + GEMM2: block = 64 nodes.
// Phase A: wave w computes g rows [w*16, w*16+16) serially with U32-PAIRED gathers,
//          writes bf16 hi/lo to LDS.  g = dinv .* (Agg Hp)
// Phase B: out = relu(g @ W2^T + b2); W2 hi/lo frags read from global (8 KB, L1-hot).
__global__ void __launch_bounds__(256, 6)
k_aggemm(const unsigned* __restrict__ T32, const int* __restrict__ csr,
         const int* __restrict__ rp, const int* __restrict__ deg,
         const float* __restrict__ dinv,
         const __bf16* __restrict__ Whi2, const __bf16* __restrict__ Wlo2,
         const float* __restrict__ bias, float* __restrict__ out) {
  constexpr int LS = 72;                 // bf16 row stride for g tiles
  constexpr int CS = 68;                 // epilogue f32 row stride
  __shared__ __align__(16) char smem[2 * 64 * LS * 2];   // 18432 B
  __bf16* gh = (__bf16*)smem;
  __bf16* gl = gh + 64 * LS;
  float*  cl = (float*)smem;             // epilogue overlay (17408 B)

  const int t = threadIdx.x;
  const int l = t & 63;
  const int w = t >> 6;
  const int s = l >> 5;
  const int fp = l & 31;
  const int rowbase = blockIdx.x * 64;

  // ---- phase A: 16 nodes per wave, u32-paired gathers
  for (int i = 0; i < 16; ++i) {
    const int node = rowbase + w * 16 + i;
    const bool va = node < NN;
    float acc0 = 0.f, acc1 = 0.f;
    const int start = va ? rp[node] : 0;
    const int len = va ? deg[node] : 0;
    for (int base = 0; base < len; base += 64) {
      int m = min(64, len - base);
      int idx = (l < m) ? csr[start + base + l] : 0;
      for (int c0 = 0; c0 < m; c0 += 16) {
        float p0 = 0.f, p1 = 0.f;
        #pragma unroll
        for (int j = 0; j < 8; ++j) {
          int e = c0 + 2 * j + s;
          int src = __shfl(idx, e & 63);
          unsigned u = T32[(size_t)src * 32 + fp];
          bool ok = e < m;
          p0 += ok ? __uint_as_float(u << 16) : 0.f;
          p1 += ok ? __uint_as_float(u & 0xFFFF0000u) : 0.f;
        }
        acc0 += p0;
        acc1 += p1;
      }
    }
    acc0 += __shfl_xor(acc0, 32);
    acc1 += __shfl_xor(acc1, 32);
    float g0 = 0.f, g1 = 0.f;
    if (va) {
      unsigned su = T32[(size_t)node * 32 + fp];
      acc0 += __uint_as_float(su << 16);
      acc1 += __uint_as_float(su & 0xFFFF0000u);
      float dv = dinv[node];
      g0 = dv * acc0;
      g1 = dv * acc1;
    }
    __bf16 h0 = (__bf16)g0, h1 = (__bf16)g1;
    __bf16 lo0 = (__bf16)(g0 - (float)h0), lo1 = (__bf16)(g1 - (float)h1);
    if (s == 0) {
      const int r = w * 16 + i;
      unsigned hp, lp;
      {
        unsigned short a = *(unsigned short*)&h0, b = *(unsigned short*)&h1;
        hp = (unsigned)a | ((unsigned)b << 16);
        unsigned short c = *(unsigned short*)&lo0, d = *(unsigned short*)&lo1;
        lp = (unsigned)c | ((unsigned)d << 16);
      }
      *reinterpret_cast<unsigned*>(&gh[r * LS + fp * 2]) = hp;
      *reinterpret_cast<unsigned*>(&gl[r * LS + fp * 2]) = lp;
    }
  }
  __syncthreads();

  // ---- phase B: MFMA, wave = 16-col slab
  const int wc = w * 16;
  f32x4 acc[4];
  #pragma unroll
  for (int rt = 0; rt < 4; ++rt) acc[rt] = (f32x4){0.f, 0.f, 0.f, 0.f};
  #pragma unroll
  for (int kc = 0; kc < 2; ++kc) {
    const size_t wo = (size_t)(wc + (l & 15)) * HID + kc * 32 + (l >> 4) * 8;
    bf16v8 bh = *reinterpret_cast<const bf16v8*>(Whi2 + wo);
    bf16v8 bl = *reinterpret_cast<const bf16v8*>(Wlo2 + wo);
    #pragma unroll
    for (int rt = 0; rt < 4; ++rt) {
      const int ao = (rt * 16 + (l & 15)) * LS + kc * 32 + (l >> 4) * 8;
      bf16v8 ah = *reinterpret_cast<const bf16v8*>(&gh[ao]);
      bf16v8 al = *reinterpret_cast<const bf16v8*>(&gl[ao]);
      acc[rt] = __builtin_amdgcn_mfma_f32_16x16x32_bf16(ah, bh, acc[rt], 0, 0, 0);
      acc[rt] = __builtin_amdgcn_mfma_f32_16x16x32_bf16(al, bh, acc[rt], 0, 0, 0);
      acc[rt] = __builtin_amdgcn_mfma_f32_16x16x32_bf16(ah, bl, acc[rt], 0, 0, 0);
    }
  }
  __syncthreads();                       // gh/gl dead; overlay cl
  #pragma unroll
  for (int rt = 0; rt < 4; ++rt)
    #pragma unroll
    for (int j = 0; j < 4; ++j)
      cl[(rt * 16 + (l >> 4) * 4 + j) * CS + wc + (l & 15)] = acc[rt][j];
  __syncthreads();

  const int r = t >> 2, cc = (t & 3) * 16;
  const int grow = rowbase + r;
  if (grow < NN) {
    float* yp = out + (size_t)grow * HID + cc;
    #pragma unroll
    for (int c4 = 0; c4 < 4; ++c4) {
      float4 o;
      o.x = fmaxf(cl[r * CS + cc + c4 * 4 + 0] + bias[cc + c4 * 4 + 0], 0.f);
      o.y = fmaxf(cl[r * CS + cc + c4 * 4 + 1] + bias[cc + c4 * 4 + 1], 0.f);
      o.z = fmaxf(cl[r * CS + cc + c4 * 4 + 2] + bias[cc + c4 * 4 + 2], 0.f);
      o.w = fmaxf(cl[r * CS + cc + c4 * 4 + 3] + bias[cc + c4 * 4 + 3], 0.f);
      *reinterpret_cast<float4*>(yp + c4 * 4) = o;
    }
  }
}

extern "C" void kernel_launch(void* const* d_in, const int* in_sizes, int n_in,
                              void* d_out, int out_size, void* d_ws, size_t ws_size,
                              hipStream_t stream) {
  const float* x  = (const float*)d_in[0];
  const int*   ed = (const int*)d_in[1];   // int32 per harness contract
  const float* W1 = (const float*)d_in[2];
  const float* b1 = (const float*)d_in[3];
  const float* W2 = (const float*)d_in[4];
  const float* b2 = (const float*)d_in[5];
  float* out = (float*)d_out;

  char* ws = (char*)d_ws;
  size_t off = 0;
  auto alloc = [&](size_t bytes) {
    char* p = ws + off;
    off = (off + bytes + 255) & ~(size_t)255;
    return p;
  };
  int*      deg    = (int*)alloc((size_t)NN * 4);
  float*    dinv   = (float*)alloc((size_t)NN * 4);
  int*      rp     = (int*)alloc((size_t)NN * 4);
  int*      gcur   = (int*)alloc((size_t)NB * 4);
  unsigned* binned = (unsigned*)alloc((size_t)NB * CAP * 4);     // 12.8 MB
  int*      csr    = (int*)alloc((size_t)NB * CAP * 4);          // 12.8 MB
  unsigned* T1     = (unsigned*)alloc((size_t)NN * HID * 2);     // 12.8 MB bf16 t1' (u32 view)
  unsigned* Hp     = (unsigned*)alloc((size_t)NN * HID * 2);     // 12.8 MB bf16 h' (u32 view)
  __bf16*   Whi1   = (__bf16*)alloc((size_t)HID * KIN * 2);
  __bf16*   Wlo1   = (__bf16*)alloc((size_t)HID * KIN * 2);
  __bf16*   Whi2   = (__bf16*)alloc((size_t)HID * HID * 2);
  __bf16*   Wlo2   = (__bf16*)alloc((size_t)HID * HID * 2);

  // ---- preprocessing: 3 launches
  k_wconv2z<<<(HID * KIN + HID * HID + 255) / 256, 256, 0, stream>>>(W1, Whi1, Wlo1, W2, Whi2, Wlo2, gcur);
  k_bin1p<<<NBK, 256, 0, stream>>>(ed, gcur, binned);
  k_degcsr<<<NB, 256, 0, stream>>>(binned, gcur, deg, dinv, rp, csr);

  const int GB = (NN + 63) / 64;  // 1563 blocks

  // layer 1: T1(bf16) = dinv .* (x @ W1^T) ; Hp(bf16) = dinv .* relu(dinv.*(Agg T1) + b1)
  k_gemm<KIN, 0><<<GB, 256, 0, stream>>>(x, Whi1, Wlo1, dinv, b1, (void*)T1);
  k_agg<<<NN / 4, 256, 0, stream>>>(T1, csr, rp, deg, dinv, b1, Hp);

  // layer 2 fused: out = relu((dinv .* Agg Hp) @ W2^T + b2)
  k_aggemm<<<GB, 256, 0, stream>>>(Hp, csr, rp, deg, dinv, Whi2, Wlo2, b2, out);
}

// Round 20
// 144.251 us; speedup vs baseline: 1.0946x; 1.0088x over previous
//
#include <hip/hip_runtime.h>

static constexpr int NN  = 100000;   // nodes
static constexpr int NE  = 1200000;  // edges
static constexpr int KIN = 256;      // input dim
static constexpr int HID = 64;       // hidden == output dim

static constexpr int BSH   = 7;                        // log2 nodes-per-bucket
static constexpr int NPB   = 1 << BSH;                 // 128 nodes per bucket
static constexpr int NB    = (NN + NPB - 1) / NPB;     // 782 buckets
static constexpr int CAP   = 4096;                     // fixed edge capacity per bucket
static constexpr int CHUNK = 8192;                     // edges per binning block
static constexpr int NBK   = (NE + CHUNK - 1) / CHUNK; // 147 binning blocks

typedef __attribute__((ext_vector_type(8))) __bf16 bf16v8;
typedef __attribute__((ext_vector_type(4))) float f32x4;

// ---------- bf16 helpers (exact widen; RNE narrow)
__device__ __forceinline__ float bf2f(unsigned short u) {
  return __uint_as_float(((unsigned int)u) << 16);
}
__device__ __forceinline__ unsigned short f2bf(float f) {
  unsigned int b = __float_as_uint(f);
  return (unsigned short)((b + 0x7FFFu + ((b >> 16) & 1u)) >> 16);
}

// ---------- W tables fp32 -> bf16 hi/lo + zero the bucket cursors (one launch)
__global__ void k_wconv2z(const float* __restrict__ W1, __bf16* __restrict__ Whi1, __bf16* __restrict__ Wlo1,
                          const float* __restrict__ W2, __bf16* __restrict__ Whi2, __bf16* __restrict__ Wlo2,
                          int* __restrict__ gcur) {
  int i = blockIdx.x * 256 + threadIdx.x;
  constexpr int n1 = HID * KIN;
  if (i < n1) {
    float v = W1[i];
    __bf16 h = (__bf16)v;
    Whi1[i] = h;
    Wlo1[i] = (__bf16)(v - (float)h);
  } else if (i < n1 + HID * HID) {
    int j = i - n1;
    float v = W2[j];
    __bf16 h = (__bf16)v;
    Whi2[j] = h;
    Wlo2[j] = (__bf16)(v - (float)h);
  }
  if (i < NB) gcur[i] = 0;
}

// ---------- single-pass binning into fixed-capacity bucket regions.
__global__ void __launch_bounds__(256) k_bin1p(const int* __restrict__ ed, int* __restrict__ gcur,
                                               unsigned* __restrict__ binned) {
  __shared__ int lcnt[NB];
  __shared__ int lbase[NB];
  int t = threadIdx.x, blk = blockIdx.x;
  for (int i = t; i < NB; i += 256) lcnt[i] = 0;
  __syncthreads();
  int base = blk * CHUNK;
  #pragma unroll
  for (int it = 0; it < CHUNK / 256; ++it) {          // pass 1: count
    int e = base + it * 256 + t;
    if (e < NE) atomicAdd(&lcnt[ed[NE + e] >> BSH], 1);
  }
  __syncthreads();
  for (int i = t; i < NB; i += 256) {                  // reserve ranges
    int c = lcnt[i];
    lbase[i] = (c > 0) ? atomicAdd(&gcur[i], c) : 0;
    lcnt[i] = 0;                                       // reuse as rank counter
  }
  __syncthreads();
  #pragma unroll
  for (int it = 0; it < CHUNK / 256; ++it) {          // pass 2: scatter (ed chunk L2-hot)
    int e = base + it * 256 + t;
    if (e < NE) {
      int src = ed[e];
      int dst = ed[NE + e];
      int b = dst >> BSH;
      int r = atomicAdd(&lcnt[b], 1);
      binned[(size_t)b * CAP + lbase[b] + r] = (unsigned)src | ((unsigned)(dst & (NPB - 1)) << 17);
    }
  }
}

// ---------- fused per-bucket: degree + dinv + rp + CSR scatter (window L2-hot)
__global__ void __launch_bounds__(256) k_degcsr(const unsigned* __restrict__ binned,
                                                const int* __restrict__ gcur,
                                                int* __restrict__ deg, float* __restrict__ dinv,
                                                int* __restrict__ rp, int* __restrict__ csr) {
  __shared__ int d[NPB];
  __shared__ int sc[NPB];
  __shared__ int cur[NPB];
  int t = threadIdx.x, b = blockIdx.x;
  if (t < NPB) { d[t] = 0; cur[t] = 0; }
  __syncthreads();
  const int n = gcur[b];
  const unsigned* win = binned + (size_t)b * CAP;
  for (int i = t; i < n; i += 256) atomicAdd(&d[win[i] >> 17], 1);
  __syncthreads();
  if (t < NPB) sc[t] = d[t];
  __syncthreads();
  #pragma unroll
  for (int off = 1; off < NPB; off <<= 1) {
    int x = (t < NPB && t >= off) ? sc[t - off] : 0;
    __syncthreads();
    if (t < NPB) sc[t] += x;
    __syncthreads();
  }
  if (t < NPB) {
    int node = b * NPB + t;
    if (node < NN) {
      deg[node] = d[t];
      dinv[node] = rsqrtf((float)(d[t] + 1));
      rp[node] = b * CAP + sc[t] - d[t];
    }
  }
  __syncthreads();
  for (int i = t; i < n; i += 256) {
    unsigned u = win[i];
    int src = (int)(u & 0x1FFFFu);
    int dl  = (int)(u >> 17);
    int r = atomicAdd(&cur[dl], 1);
    csr[(size_t)b * CAP + (sc[dl] - d[dl]) + r] = src;
  }
}

// ---------- MFMA GEMM with register prefetch of next k-tile.
// Y = X @ W^T via bf16 hi/lo 3-term split (~fp32 accurate).
// MODE 0: Y(bf16) = dinv[r]*acc; MODE 1: Y(fp32) = relu(acc + bias).
template<int K, int MODE>
__global__ void __launch_bounds__(256, 4)
k_gemm(const float* __restrict__ X, const __bf16* __restrict__ Whi, const __bf16* __restrict__ Wlo,
       const float* __restrict__ dinv, const float* __restrict__ bias, void* __restrict__ Yv) {
  constexpr int KT = 32;
  constexpr int NT = K / KT;
  constexpr int LS = 40;
  constexpr int CS = 68;
  __shared__ __align__(16) char smem[4 * 64 * LS * 2];
  __bf16* xh = (__bf16*)smem;
  __bf16* xl = xh + 64 * LS;
  __bf16* wh = xl + 64 * LS;
  __bf16* wl = wh + 64 * LS;
  float*  cl = (float*)smem;

  const int t = threadIdx.x;
  const int l = t & 63;
  const int wc = (t >> 6) * 16;
  const int rowbase = blockIdx.x * 64;

  f32x4 acc[4];
  #pragma unroll
  for (int rt = 0; rt < 4; ++rt) acc[rt] = (f32x4){0.f, 0.f, 0.f, 0.f};

  const int sr = t >> 2;
  const int kc = (t & 3) * 8;
  const int gr = rowbase + sr;
  const float* xrow = X + (size_t)gr * K + kc;

  float4 pa, pb;
  bf16v8 pwh, pwl;

  auto loadTile = [&](int kt) {
    pa = make_float4(0.f, 0.f, 0.f, 0.f);
    pb = pa;
    if (gr < NN) {
      pa = *reinterpret_cast<const float4*>(xrow + kt * KT);
      pb = *reinterpret_cast<const float4*>(xrow + kt * KT + 4);
    }
    size_t wo = (size_t)sr * K + kt * KT + kc;
    pwh = *reinterpret_cast<const bf16v8*>(Whi + wo);
    pwl = *reinterpret_cast<const bf16v8*>(Wlo + wo);
  };
  auto storeTile = [&]() {
    float e[8] = {pa.x, pa.y, pa.z, pa.w, pb.x, pb.y, pb.z, pb.w};
    bf16v8 hv, lv;
    #pragma unroll
    for (int j = 0; j < 8; ++j) {
      __bf16 h = (__bf16)e[j];
      hv[j] = h;
      lv[j] = (__bf16)(e[j] - (float)h);
    }
    *reinterpret_cast<bf16v8*>(&xh[sr * LS + kc]) = hv;
    *reinterpret_cast<bf16v8*>(&xl[sr * LS + kc]) = lv;
    *reinterpret_cast<bf16v8*>(&wh[sr * LS + kc]) = pwh;
    *reinterpret_cast<bf16v8*>(&wl[sr * LS + kc]) = pwl;
  };

  loadTile(0);
  storeTile();
  __syncthreads();

  for (int kt = 0; kt < NT; ++kt) {
    if (kt + 1 < NT) loadTile(kt + 1);   // global loads in flight during compute

    const int bo = (wc + (l & 15)) * LS + (l >> 4) * 8;
    bf16v8 bh = *reinterpret_cast<const bf16v8*>(&wh[bo]);
    bf16v8 bl = *reinterpret_cast<const bf16v8*>(&wl[bo]);
    #pragma unroll
    for (int rt = 0; rt < 4; ++rt) {
      const int ao = (rt * 16 + (l & 15)) * LS + (l >> 4) * 8;
      bf16v8 ah = *reinterpret_cast<const bf16v8*>(&xh[ao]);
      bf16v8 al = *reinterpret_cast<const bf16v8*>(&xl[ao]);
      acc[rt] = __builtin_amdgcn_mfma_f32_16x16x32_bf16(ah, bh, acc[rt], 0, 0, 0);
      acc[rt] = __builtin_amdgcn_mfma_f32_16x16x32_bf16(al, bh, acc[rt], 0, 0, 0);
      acc[rt] = __builtin_amdgcn_mfma_f32_16x16x32_bf16(ah, bl, acc[rt], 0, 0, 0);
    }

    if (kt + 1 < NT) {
      __syncthreads();                   // tile kt fully consumed
      storeTile();
      __syncthreads();                   // tile kt+1 visible
    }
  }

  __syncthreads();
  #pragma unroll
  for (int rt = 0; rt < 4; ++rt)
    #pragma unroll
    for (int j = 0; j < 4; ++j)
      cl[(rt * 16 + (l >> 4) * 4 + j) * CS + wc + (l & 15)] = acc[rt][j];
  __syncthreads();

  const int r = t >> 2, cc = (t & 3) * 16;
  const int grow = rowbase + r;
  if (grow < NN) {
    if (MODE == 0) {
      float dv = dinv[grow];
      bf16v8 o0, o1;
      #pragma unroll
      for (int j = 0; j < 8; ++j) o0[j] = (__bf16)(cl[r * CS + cc + j] * dv);
      #pragma unroll
      for (int j = 0; j < 8; ++j) o1[j] = (__bf16)(cl[r * CS + cc + 8 + j] * dv);
      __bf16* yp = (__bf16*)Yv + (size_t)grow * HID + cc;
      *reinterpret_cast<bf16v8*>(yp) = o0;
      *reinterpret_cast<bf16v8*>(yp + 8) = o1;
    } else {
      float* yp = (float*)Yv + (size_t)grow * HID + cc;
      #pragma unroll
      for (int c4 = 0; c4 < 4; ++c4) {
        float4 o;
        o.x = fmaxf(cl[r * CS + cc + c4 * 4 + 0] + bias[cc + c4 * 4 + 0], 0.f);
        o.y = fmaxf(cl[r * CS + cc + c4 * 4 + 1] + bias[cc + c4 * 4 + 1], 0.f);
        o.z = fmaxf(cl[r * CS + cc + c4 * 4 + 2] + bias[cc + c4 * 4 + 2], 0.f);
        o.w = fmaxf(cl[r * CS + cc + c4 * 4 + 3] + bias[cc + c4 * 4 + 3], 0.f);
        *reinterpret_cast<float4*>(yp + c4 * 4) = o;
      }
    }
  }
}

// ---------- standalone agg (layer 1), U32-PAIRED gathers: lane = (edge-slot l>>5,
// feature-pair l&31). One dword gather = 2 edges x full 64-feature row (256 B);
// u32 unpack gives both bf16 features in 2 VALU ops. One shfl_xor(32) merges slots.
// O(bf16) = dinv*relu(dinv*sum + bias).
__global__ void __launch_bounds__(256, 8)
k_agg(const unsigned* __restrict__ T32, const int* __restrict__ csr,
      const int* __restrict__ rp, const int* __restrict__ deg,
      const float* __restrict__ dinv, const float* __restrict__ bias,
      unsigned* __restrict__ Ov32) {
  const int t = threadIdx.x;
  const int node = blockIdx.x * 4 + (t >> 6);
  const int lane = t & 63;
  const int s = lane >> 5;          // edge slot (0/1)
  const int fp = lane & 31;         // feature pair index
  float acc0 = 0.f, acc1 = 0.f;
  const int start = rp[node];
  const int len = deg[node];
  for (int base = 0; base < len; base += 64) {
    int m = min(64, len - base);
    int idx = (lane < m) ? csr[start + base + lane] : 0;
    for (int c0 = 0; c0 < m; c0 += 16) {     // 16 edges per outer iter = 8 gather instrs
      float p0 = 0.f, p1 = 0.f;
      #pragma unroll
      for (int i = 0; i < 8; ++i) {
        int e = c0 + 2 * i + s;
        int src = __shfl(idx, e & 63);
        unsigned u = T32[(size_t)src * 32 + fp];     // 2 bf16 features
        bool ok = e < m;
        p0 += ok ? __uint_as_float(u << 16) : 0.f;
        p1 += ok ? __uint_as_float(u & 0xFFFF0000u) : 0.f;
      }
      acc0 += p0;
      acc1 += p1;
    }
  }
  acc0 += __shfl_xor(acc0, 32);       // merge edge slots
  acc1 += __shfl_xor(acc1, 32);
  unsigned su = T32[(size_t)node * 32 + fp];   // self-loop (pre-scaled)
  acc0 += __uint_as_float(su << 16);
  acc1 += __uint_as_float(su & 0xFFFF0000u);
  float dv = dinv[node];
  float h0 = dv * fmaxf(fmaf(dv, acc0, bias[fp * 2]), 0.f);
  float h1 = dv * fmaxf(fmaf(dv, acc1, bias[fp * 2 + 1]), 0.f);
  if (s == 0) {
    unsigned pack = (unsigned)f2bf(h0) | ((unsigned)f2bf(h1) << 16);
    Ov32[(size_t)node * 32 + fp] = pack;
  }
}

// ---------- FUSED agg(layer2) + GEMM2: block = 64 nodes, 512 threads (8 waves).
// Phase A: wave w aggregates 8 rows [w*8, w*8+8) with u32-paired gathers (half the
//          serial latency of the 256-thread version), writes bf16 hi/lo to LDS.
// Phase B: 8 waves: col-slab wc=(w&3)*16, row-tile pair rt0=(w>>2)*2, acc[2] each;
//          waves w and w+4 share W2 fragments (L1 broadcast).
__global__ void __launch_bounds__(512, 8)
k_aggemm(const unsigned* __restrict__ T32, const int* __restrict__ csr,
         const int* __restrict__ rp, const int* __restrict__ deg,
         const float* __restrict__ dinv,
         const __bf16* __restrict__ Whi2, const __bf16* __restrict__ Wlo2,
         const float* __restrict__ bias, float* __restrict__ out) {
  constexpr int LS = 72;                 // bf16 row stride for g tiles
  constexpr int CS = 68;                 // epilogue f32 row stride
  __shared__ __align__(16) char smem[2 * 64 * LS * 2];   // 18432 B
  __bf16* gh = (__bf16*)smem;
  __bf16* gl = gh + 64 * LS;
  float*  cl = (float*)smem;             // epilogue overlay (17408 B)

  const int t = threadIdx.x;
  const int l = t & 63;
  const int w = t >> 6;                  // 0..7
  const int s = l >> 5;
  const int fp = l & 31;
  const int rowbase = blockIdx.x * 64;

  // ---- phase A: 8 nodes per wave, u32-paired gathers
  for (int i = 0; i < 8; ++i) {
    const int node = rowbase + w * 8 + i;
    const bool va = node < NN;
    float acc0 = 0.f, acc1 = 0.f;
    const int start = va ? rp[node] : 0;
    const int len = va ? deg[node] : 0;
    for (int base = 0; base < len; base += 64) {
      int m = min(64, len - base);
      int idx = (l < m) ? csr[start + base + l] : 0;
      for (int c0 = 0; c0 < m; c0 += 16) {
        float p0 = 0.f, p1 = 0.f;
        #pragma unroll
        for (int j = 0; j < 8; ++j) {
          int e = c0 + 2 * j + s;
          int src = __shfl(idx, e & 63);
          unsigned u = T32[(size_t)src * 32 + fp];
          bool ok = e < m;
          p0 += ok ? __uint_as_float(u << 16) : 0.f;
          p1 += ok ? __uint_as_float(u & 0xFFFF0000u) : 0.f;
        }
        acc0 += p0;
        acc1 += p1;
      }
    }
    acc0 += __shfl_xor(acc0, 32);
    acc1 += __shfl_xor(acc1, 32);
    float g0 = 0.f, g1 = 0.f;
    if (va) {
      unsigned su = T32[(size_t)node * 32 + fp];
      acc0 += __uint_as_float(su << 16);
      acc1 += __uint_as_float(su & 0xFFFF0000u);
      float dv = dinv[node];
      g0 = dv * acc0;
      g1 = dv * acc1;
    }
    __bf16 h0 = (__bf16)g0, h1 = (__bf16)g1;
    __bf16 lo0 = (__bf16)(g0 - (float)h0), lo1 = (__bf16)(g1 - (float)h1);
    if (s == 0) {
      const int r = w * 8 + i;
      unsigned hp, lp;
      {
        unsigned short a = *(unsigned short*)&h0, b = *(unsigned short*)&h1;
        hp = (unsigned)a | ((unsigned)b << 16);
        unsigned short c = *(unsigned short*)&lo0, d = *(unsigned short*)&lo1;
        lp = (unsigned)c | ((unsigned)d << 16);
      }
      *reinterpret_cast<unsigned*>(&gh[r * LS + fp * 2]) = hp;
      *reinterpret_cast<unsigned*>(&gl[r * LS + fp * 2]) = lp;
    }
  }
  __syncthreads();

  // ---- phase B: MFMA; wave w -> cols [wc,wc+16), row-tiles rt0..rt0+1
  const int wc = (w & 3) * 16;
  const int rt0 = (w >> 2) * 2;
  f32x4 acc[2];
  #pragma unroll
  for (int rr = 0; rr < 2; ++rr) acc[rr] = (f32x4){0.f, 0.f, 0.f, 0.f};
  #pragma unroll
  for (int kc = 0; kc < 2; ++kc) {
    const size_t wo = (size_t)(wc + (l & 15)) * HID + kc * 32 + (l >> 4) * 8;
    bf16v8 bh = *reinterpret_cast<const bf16v8*>(Whi2 + wo);
    bf16v8 bl = *reinterpret_cast<const bf16v8*>(Wlo2 + wo);
    #pragma unroll
    for (int rr = 0; rr < 2; ++rr) {
      const int ao = ((rt0 + rr) * 16 + (l & 15)) * LS + kc * 32 + (l >> 4) * 8;
      bf16v8 ah = *reinterpret_cast<const bf16v8*>(&gh[ao]);
      bf16v8 al = *reinterpret_cast<const bf16v8*>(&gl[ao]);
      acc[rr] = __builtin_amdgcn_mfma_f32_16x16x32_bf16(ah, bh, acc[rr], 0, 0, 0);
      acc[rr] = __builtin_amdgcn_mfma_f32_16x16x32_bf16(al, bh, acc[rr], 0, 0, 0);
      acc[rr] = __builtin_amdgcn_mfma_f32_16x16x32_bf16(ah, bl, acc[rr], 0, 0, 0);
    }
  }
  __syncthreads();                       // gh/gl dead; overlay cl
  #pragma unroll
  for (int rr = 0; rr < 2; ++rr)
    #pragma unroll
    for (int j = 0; j < 4; ++j)
      cl[((rt0 + rr) * 16 + (l >> 4) * 4 + j) * CS + wc + (l & 15)] = acc[rr][j];
  __syncthreads();

  const int r = t >> 3, cc = (t & 7) * 8;
  const int grow = rowbase + r;
  if (grow < NN) {
    float* yp = out + (size_t)grow * HID + cc;
    #pragma unroll
    for (int c4 = 0; c4 < 2; ++c4) {
      float4 o;
      o.x = fmaxf(cl[r * CS + cc + c4 * 4 + 0] + bias[cc + c4 * 4 + 0], 0.f);
      o.y = fmaxf(cl[r * CS + cc + c4 * 4 + 1] + bias[cc + c4 * 4 + 1], 0.f);
      o.z = fmaxf(cl[r * CS + cc + c4 * 4 + 2] + bias[cc + c4 * 4 + 2], 0.f);
      o.w = fmaxf(cl[r * CS + cc + c4 * 4 + 3] + bias[cc + c4 * 4 + 3], 0.f);
      *reinterpret_cast<float4*>(yp + c4 * 4) = o;
    }
  }
}

extern "C" void kernel_launch(void* const* d_in, const int* in_sizes, int n_in,
                              void* d_out, int out_size, void* d_ws, size_t ws_size,
                              hipStream_t stream) {
  const float* x  = (const float*)d_in[0];
  const int*   ed = (const int*)d_in[1];   // int32 per harness contract
  const float* W1 = (const float*)d_in[2];
  const float* b1 = (const float*)d_in[3];
  const float* W2 = (const float*)d_in[4];
  const float* b2 = (const float*)d_in[5];
  float* out = (float*)d_out;

  char* ws = (char*)d_ws;
  size_t off = 0;
  auto alloc = [&](size_t bytes) {
    char* p = ws + off;
    off = (off + bytes + 255) & ~(size_t)255;
    return p;
  };
  int*      deg    = (int*)alloc((size_t)NN * 4);
  float*    dinv   = (float*)alloc((size_t)NN * 4);
  int*      rp     = (int*)alloc((size_t)NN * 4);
  int*      gcur   = (int*)alloc((size_t)NB * 4);
  unsigned* binned = (unsigned*)alloc((size_t)NB * CAP * 4);     // 12.8 MB
  int*      csr    = (int*)alloc((size_t)NB * CAP * 4);          // 12.8 MB
  unsigned* T1     = (unsigned*)alloc((size_t)NN * HID * 2);     // 12.8 MB bf16 t1' (u32 view)
  unsigned* Hp     = (unsigned*)alloc((size_t)NN * HID * 2);     // 12.8 MB bf16 h' (u32 view)
  __bf16*   Whi1   = (__bf16*)alloc((size_t)HID * KIN * 2);
  __bf16*   Wlo1   = (__bf16*)alloc((size_t)HID * KIN * 2);
  __bf16*   Whi2   = (__bf16*)alloc((size_t)HID * HID * 2);
  __bf16*   Wlo2   = (__bf16*)alloc((size_t)HID * HID * 2);

  // ---- preprocessing: 3 launches
  k_wconv2z<<<(HID * KIN + HID * HID + 255) / 256, 256, 0, stream>>>(W1, Whi1, Wlo1, W2, Whi2, Wlo2, gcur);
  k_bin1p<<<NBK, 256, 0, stream>>>(ed, gcur, binned);
  k_degcsr<<<NB, 256, 0, stream>>>(binned, gcur, deg, dinv, rp, csr);

  const int GB = (NN + 63) / 64;  // 1563 blocks

  // layer 1: T1(bf16) = dinv .* (x @ W1^T) ; Hp(bf16) = dinv .* relu(dinv.*(Agg T1) + b1)
  k_gemm<KIN, 0><<<GB, 256, 0, stream>>>(x, Whi1, Wlo1, dinv, b1, (void*)T1);
  k_agg<<<NN / 4, 256, 0, stream>>>(T1, csr, rp, deg, dinv, b1, Hp);

  // layer 2 fused: out = relu((dinv .* Agg Hp) @ W2^T + b2)
  k_aggemm<<<GB, 512, 0, stream>>>(Hp, csr, rp, deg, dinv, Whi2, Wlo2, b2, out);
}